// Round 1
// baseline (352.481 us; speedup 1.0000x reference)
//
#include <hip/hip_runtime.h>

// ForwardForwardCountingLayer forward:
//   per (b,o): vals[i] = (et==2 ? 1-x[b,i] : x[b,i]) + (et==0 ? off : 0)
//   off = is_tnorm ? +10 : -10 ; out = is_tnorm ? min_i vals : max_i vals
// Memory-bound on the 268 MB edge_type_idx read. One wave per output row.

constexpr int B = 64;
constexpr int I = 1024;
constexpr int O = 1024;
constexpr int ROWS_PER_BLOCK = 4;   // 4 waves x 64 lanes = 256 threads

__global__ __launch_bounds__(256) void ffcl_kernel(
    const float* __restrict__ x,       // [B, I]
    const int*   __restrict__ et,      // [B, O, I]
    const int*   __restrict__ op,      // [O]
    float*       __restrict__ out)     // [B, O]
{
    __shared__ float xs[I];

    const int t   = threadIdx.x;
    const int r0  = blockIdx.x * ROWS_PER_BLOCK;   // first row of this block
    const int b   = r0 >> 10;                      // r0 / O (4 | 1024, so b uniform in block)

    // Stage x[b,:] (4 KB) into LDS: 256 threads x float4, fully coalesced.
    {
        const float4* src = reinterpret_cast<const float4*>(x + (size_t)b * I);
        reinterpret_cast<float4*>(xs)[t] = src[t];
    }
    __syncthreads();

    const int wid  = t >> 6;
    const int lane = t & 63;
    const int r    = r0 + wid;         // global row = b*O + o
    const int o    = r & (O - 1);

    const bool  is_t = (op[o] == 0);
    const float sgn  = is_t ? -1.0f : 1.0f;   // min(v) = -max(-v); *(+-1) is exact
    const float off  = is_t ? 10.0f : -10.0f;

    const int4* etp = reinterpret_cast<const int4*>(et + (size_t)r * I);

    float acc = -3.0e38f;
    #pragma unroll
    for (int j = 0; j < 4; ++j) {
        const int col = j * 256 + lane * 4;    // lane-contiguous int4 -> 1 KB/wave/load
        const int4  e  = etp[col >> 2];
        const float4 xv = *reinterpret_cast<const float4*>(&xs[col]);

        float v;
        v = (e.x == 2) ? 1.0f - xv.x : xv.x;  v += (e.x == 0) ? off : 0.0f;  acc = fmaxf(acc, sgn * v);
        v = (e.y == 2) ? 1.0f - xv.y : xv.y;  v += (e.y == 0) ? off : 0.0f;  acc = fmaxf(acc, sgn * v);
        v = (e.z == 2) ? 1.0f - xv.z : xv.z;  v += (e.z == 0) ? off : 0.0f;  acc = fmaxf(acc, sgn * v);
        v = (e.w == 2) ? 1.0f - xv.w : xv.w;  v += (e.w == 0) ? off : 0.0f;  acc = fmaxf(acc, sgn * v);
    }

    // wave-64 butterfly max-reduce
    #pragma unroll
    for (int s = 32; s > 0; s >>= 1)
        acc = fmaxf(acc, __shfl_xor(acc, s, 64));

    if (lane == 0)
        out[r] = sgn * acc;
}

extern "C" void kernel_launch(void* const* d_in, const int* in_sizes, int n_in,
                              void* d_out, int out_size, void* d_ws, size_t ws_size,
                              hipStream_t stream) {
    const float* x  = (const float*)d_in[0];
    const int*   et = (const int*)d_in[1];
    const int*   op = (const int*)d_in[2];
    float*       out = (float*)d_out;

    const int n_rows = B * O;                       // 65536
    const int grid   = n_rows / ROWS_PER_BLOCK;     // 16384
    ffcl_kernel<<<grid, 256, 0, stream>>>(x, et, op, out);
}

// Round 3
// 332.596 us; speedup vs baseline: 1.0598x; 1.0598x over previous
//
#include <hip/hip_runtime.h>

// ForwardForwardCountingLayer forward:
//   per (b,o): vals[i] = (et==2 ? 1-x[b,i] : x[b,i]) + (et==0 ? off : 0)
//   off = is_tnorm ? +10 : -10 ; out = is_tnorm ? min_i vals : max_i vals
// Memory-bound on the 268 MB edge_type_idx stream (no reuse -> nontemporal).
// 2 rows per wave, all 8 int4 loads in flight before consumption (MLP).

constexpr int B = 64;
constexpr int I = 1024;
constexpr int O = 1024;
constexpr int ROWS_PER_BLOCK = 8;   // 4 waves x 2 rows

typedef int   iv4 __attribute__((ext_vector_type(4)));   // native vector: OK for nontemporal builtin
typedef float fv4 __attribute__((ext_vector_type(4)));

__global__ __launch_bounds__(256) void ffcl_kernel(
    const float* __restrict__ x,       // [B, I]
    const int*   __restrict__ et,      // [B, O, I]
    const int*   __restrict__ op,      // [O]
    float*       __restrict__ out)     // [B, O]
{
    __shared__ float xs[I];

    const int t      = threadIdx.x;
    const int r_base = blockIdx.x * ROWS_PER_BLOCK;
    const int b      = r_base >> 10;               // 8 | 1024 -> b uniform in block

    // Stage x[b,:] (4 KB) into LDS: 256 threads x 16 B, coalesced.
    {
        const fv4* src = reinterpret_cast<const fv4*>(x + (size_t)b * I);
        reinterpret_cast<fv4*>(xs)[t] = src[t];
    }
    __syncthreads();

    const int wid  = t >> 6;
    const int lane = t & 63;
    const int r0   = r_base + wid * 2;             // global rows r0, r0+1
    const int r1   = r0 + 1;
    const int o0   = r0 & (O - 1);
    const int o1   = r1 & (O - 1);

    const bool  is_t0 = (op[o0] == 0);
    const bool  is_t1 = (op[o1] == 0);
    const float sgn0  = is_t0 ? -1.0f : 1.0f;      // min(v) = -max(-v); *(+-1) exact
    const float sgn1  = is_t1 ? -1.0f : 1.0f;
    const float off0  = is_t0 ? 10.0f : -10.0f;
    const float off1  = is_t1 ? 10.0f : -10.0f;

    const iv4* p0 = reinterpret_cast<const iv4*>(et + (size_t)r0 * I);
    const iv4* p1 = reinterpret_cast<const iv4*>(et + (size_t)r1 * I);

    // Issue ALL 8 global loads (128 B/lane, 8 KB/wave in flight) before use.
    iv4 e0[4], e1[4];
    #pragma unroll
    for (int j = 0; j < 4; ++j) e0[j] = __builtin_nontemporal_load(&p0[j * 64 + lane]);
    #pragma unroll
    for (int j = 0; j < 4; ++j) e1[j] = __builtin_nontemporal_load(&p1[j * 64 + lane]);

    float acc0 = -3.0e38f, acc1 = -3.0e38f;
    #pragma unroll
    for (int j = 0; j < 4; ++j) {
        const int col = j * 256 + lane * 4;
        const fv4 xv  = *reinterpret_cast<const fv4*>(&xs[col]);

        float v;
        v = (e0[j].x == 2) ? 1.0f - xv.x : xv.x;  v += (e0[j].x == 0) ? off0 : 0.0f;  acc0 = fmaxf(acc0, sgn0 * v);
        v = (e0[j].y == 2) ? 1.0f - xv.y : xv.y;  v += (e0[j].y == 0) ? off0 : 0.0f;  acc0 = fmaxf(acc0, sgn0 * v);
        v = (e0[j].z == 2) ? 1.0f - xv.z : xv.z;  v += (e0[j].z == 0) ? off0 : 0.0f;  acc0 = fmaxf(acc0, sgn0 * v);
        v = (e0[j].w == 2) ? 1.0f - xv.w : xv.w;  v += (e0[j].w == 0) ? off0 : 0.0f;  acc0 = fmaxf(acc0, sgn0 * v);

        v = (e1[j].x == 2) ? 1.0f - xv.x : xv.x;  v += (e1[j].x == 0) ? off1 : 0.0f;  acc1 = fmaxf(acc1, sgn1 * v);
        v = (e1[j].y == 2) ? 1.0f - xv.y : xv.y;  v += (e1[j].y == 0) ? off1 : 0.0f;  acc1 = fmaxf(acc1, sgn1 * v);
        v = (e1[j].z == 2) ? 1.0f - xv.z : xv.z;  v += (e1[j].z == 0) ? off1 : 0.0f;  acc1 = fmaxf(acc1, sgn1 * v);
        v = (e1[j].w == 2) ? 1.0f - xv.w : xv.w;  v += (e1[j].w == 0) ? off1 : 0.0f;  acc1 = fmaxf(acc1, sgn1 * v);
    }

    // wave-64 butterfly max-reduce (two independent chains interleave)
    #pragma unroll
    for (int s = 32; s > 0; s >>= 1) {
        acc0 = fmaxf(acc0, __shfl_xor(acc0, s, 64));
        acc1 = fmaxf(acc1, __shfl_xor(acc1, s, 64));
    }

    if (lane == 0) {
        out[r0] = sgn0 * acc0;
        out[r1] = sgn1 * acc1;
    }
}

extern "C" void kernel_launch(void* const* d_in, const int* in_sizes, int n_in,
                              void* d_out, int out_size, void* d_ws, size_t ws_size,
                              hipStream_t stream) {
    const float* x   = (const float*)d_in[0];
    const int*   et  = (const int*)d_in[1];
    const int*   op  = (const int*)d_in[2];
    float*       out = (float*)d_out;

    const int n_rows = B * O;                       // 65536
    const int grid   = n_rows / ROWS_PER_BLOCK;     // 8192
    ffcl_kernel<<<grid, 256, 0, stream>>>(x, et, op, out);
}